// Round 10
// baseline (2509.081 us; speedup 1.0000x reference)
//
#include <hip/hip_runtime.h>
#include <math.h>

#define N_NODES 100000
#define D 256
#define C 128
#define N_EDGES 3200000

#define BROWS 128                      // rows per bucket (b = row >> 7)
#define NBUCKET ((N_NODES + BROWS - 1) / BROWS)  // 782
#define CAP 4608                       // bucket capacity (mean 4096, +8 sigma)
#define EPB 8192                       // edges per partition block
#define PBLOCKS ((N_EDGES + EPB - 1) / EPB)      // 391

typedef __attribute__((ext_vector_type(8))) short bf16x8;
typedef __attribute__((ext_vector_type(4))) float f32x4;

// ---------------------------------------------------------------------------
// helpers
// ---------------------------------------------------------------------------
__device__ __forceinline__ unsigned short f2bf(float f) {
  const unsigned int u = __float_as_uint(f);
  return (unsigned short)((u + 0x7fffu + ((u >> 16) & 1u)) >> 16);
}
__device__ __forceinline__ unsigned int pack_bf(float lo, float hi) {
  return (unsigned int)f2bf(lo) | ((unsigned int)f2bf(hi) << 16);
}
__device__ __forceinline__ float bflo(unsigned int u) {
  return __uint_as_float(u << 16);
}
__device__ __forceinline__ float bfhi(unsigned int u) {
  return __uint_as_float(u & 0xffff0000u);
}
__device__ __forceinline__ float selu1(float x) {
  const float scale = 1.0507009873554804934193349852946f;
  const float alpha = 1.6732632423543772848170429916717f;
  return x > 0.f ? scale * x : scale * alpha * (__expf(x) - 1.f);
}
// colval word: col in bits [31:15], bf16(val) sans sign (val>=0) in [14:0]
__device__ __forceinline__ unsigned int pack_rec(int col, float val) {
  return ((unsigned int)col << 15) | ((unsigned int)f2bf(val) & 0x7fffu);
}
__device__ __forceinline__ float rec_val(unsigned int r) {
  return __uint_as_float((r & 0x7fffu) << 16);
}
__device__ __forceinline__ bf16x8 packA_nt(const float* p) {
  const f32x4 a0 = __builtin_nontemporal_load(reinterpret_cast<const f32x4*>(p));
  const f32x4 a1 =
      __builtin_nontemporal_load(reinterpret_cast<const f32x4*>(p) + 1);
  union {
    unsigned int u[4];
    bf16x8 v;
  } af;
  af.u[0] = pack_bf(a0[0], a0[1]);
  af.u[1] = pack_bf(a0[2], a0[3]);
  af.u[2] = pack_bf(a1[0], a1[1]);
  af.u[3] = pack_bf(a1[2], a1[3]);
  return af.v;
}

// ---------------------------------------------------------------------------
// prep: WT[n][k] = bf16(W[k][n])  (64 KB)
// ---------------------------------------------------------------------------
__global__ __launch_bounds__(256) void prep(const float* __restrict__ W,
                                            unsigned short* __restrict__ WT) {
  const int t = blockIdx.x * blockDim.x + threadIdx.x;  // 0..32767
  const int n = t >> 8;
  const int k = t & 255;
  WT[t] = f2bf(W[k * C + n]);
}

// ---------------------------------------------------------------------------
// FUSED gemm + bucket-partition, 512-thr blocks, alternating by bid&1.
//  - gemm role (391 blocks, 8 waves each): h2 = bf16(X@W), 32 rows/wave,
//    MFMA (r8-proven body).
//  - partition role (391 blocks): 8192 edges/block; LDS histogram over 782
//    row-buckets; ONE global atomicAdd per (block,bucket) reserves a
//    contiguous segment; records written into own segments -> each 64B
//    line filled by ~one block (one XCD) -> near-full-line HBM writes.
// ---------------------------------------------------------------------------
__global__ __launch_bounds__(512) void gemm_partition(
    const float* __restrict__ X, const unsigned short* __restrict__ WT,
    unsigned short* __restrict__ h2, const int* __restrict__ row,
    const int* __restrict__ col, const float* __restrict__ vals,
    int* __restrict__ gcur, uint2* __restrict__ recs) {
  __shared__ int hist[NBUCKET];
  __shared__ int run[NBUCKET];
  __shared__ int sbase[NBUCKET];
  const int bid = blockIdx.x;
  const int tid = threadIdx.x;

  if ((bid & 1) == 0) {
    // ---------------- GEMM ----------------
    const int wid = (bid >> 1) * 8 + (tid >> 6);
    const int row0 = wid * 32;
    if (row0 >= N_NODES) return;
    const int lane = tid & 63;
    const int r = lane & 15;   // A row in tile / B col in frag
    const int kg = lane >> 4;  // k-group 0..3

    f32x4 acc[2][8];
#pragma unroll
    for (int g = 0; g < 2; ++g)
#pragma unroll
      for (int f = 0; f < 8; ++f) acc[g][f] = (f32x4){0.f, 0.f, 0.f, 0.f};

    const float* arow0 = X + (size_t)(row0 + r) * D + kg * 8;
    const float* arow1 = arow0 + 16 * D;
    for (int k0 = 0; k0 < D; k0 += 32) {
      const bf16x8 a0 = packA_nt(arow0 + k0);
      const bf16x8 a1 = packA_nt(arow1 + k0);
#pragma unroll
      for (int f = 0; f < 8; ++f) {
        const bf16x8 bf = *reinterpret_cast<const bf16x8*>(
            WT + (size_t)(f * 16 + r) * D + k0 + kg * 8);
        acc[0][f] =
            __builtin_amdgcn_mfma_f32_16x16x32_bf16(a0, bf, acc[0][f], 0, 0, 0);
        acc[1][f] =
            __builtin_amdgcn_mfma_f32_16x16x32_bf16(a1, bf, acc[1][f], 0, 0, 0);
      }
    }
    // C/D layout: col = lane&15, row = (lane>>4)*4 + reg  [m89-verified]
#pragma unroll
    for (int g = 0; g < 2; ++g)
#pragma unroll
      for (int f = 0; f < 8; ++f)
#pragma unroll
        for (int j = 0; j < 4; ++j)
          h2[(size_t)(row0 + g * 16 + kg * 4 + j) * C + f * 16 + r] =
              f2bf(acc[g][f][j]);
  } else {
    // ---------------- PARTITION ----------------
    const int pb = bid >> 1;  // 0..390
    const int e0 = pb * EPB;
    for (int i = tid; i < NBUCKET; i += 512) hist[i] = 0;
    __syncthreads();

    int rstash[16];
#pragma unroll
    for (int k = 0; k < 16; ++k) {
      const int e = e0 + k * 512 + tid;
      int r = -1;
      if (e < N_EDGES) r = __builtin_nontemporal_load(row + e);
      rstash[k] = r;
      if (r >= 0) atomicAdd(&hist[r >> 7], 1);
    }
    __syncthreads();
    for (int b = tid; b < NBUCKET; b += 512) {
      const int h = hist[b];
      sbase[b] = h ? atomicAdd(&gcur[b], h) : 0;
      run[b] = 0;
    }
    __syncthreads();
#pragma unroll
    for (int k = 0; k < 16; ++k) {
      const int r = rstash[k];
      if (r < 0) continue;
      const int e = e0 + k * 512 + tid;
      const int c = __builtin_nontemporal_load(col + e);
      const float v = __builtin_nontemporal_load(vals + e);
      const int b = r >> 7;
      const int pos = sbase[b] + atomicAdd(&run[b], 1);
      if (pos < CAP)
        recs[(size_t)b * CAP + pos] = make_uint2(pack_rec(c, v), r & (BROWS - 1));
    }
  }
}

// ---------------------------------------------------------------------------
// Gather + skip/bias + SELU. One WG (512 thr) per HALF-bucket (64 rows).
// Records streamed sequentially (broadcast loads); accumulate into a 32KB
// LDS f32 accumulator via ds_add_f32. No ELL in HBM, no slot counters.
// Lane owns channels 2l, 2l+1. 4 WGs/CU -> 32 waves/CU.
// ---------------------------------------------------------------------------
__global__ __launch_bounds__(512) void bucket_gather_selu(
    const int* __restrict__ gcur, const uint2* __restrict__ recs,
    const unsigned int* __restrict__ h2u, const float* __restrict__ skip,
    const float* __restrict__ bias, float* __restrict__ out) {
  __shared__ float acc[64 * 128];  // 32 KB
  const int tid = threadIdx.x;
  const int b = blockIdx.x >> 1;
  const int half = blockIdx.x & 1;

  for (int i = tid; i < 64 * 128; i += 512) acc[i] = 0.f;
  __syncthreads();

  int fill = gcur[b];
  fill = fill < CAP ? fill : CAP;
  const int lane = tid & 63;
  const int wv = tid >> 6;  // 0..7
  const uint2* rb = recs + (size_t)b * CAP;

  for (int i = wv; i < fill; i += 8) {
    const uint2 rec = rb[i];  // wave-uniform broadcast load
    const int lr = (int)rec.y;
    if ((lr >> 6) != half) continue;  // uniform branch
    const unsigned int cv = rec.x;
    const float v = rec_val(cv);
    const unsigned int u = h2u[(size_t)(cv >> 15) * 64 + lane];
    const int a = (lr & 63) * 128 + 2 * lane;
    atomicAdd(&acc[a], v * bflo(u));
    atomicAdd(&acc[a + 1], v * bfhi(u));
  }
  __syncthreads();

  // epilogue: 64 rows x 128 ch = 8192 f32; thread handles 16 ch of one row
  const int lrow = tid >> 3;       // 0..63
  const int ch0 = (tid & 7) * 16;  // 0,16,...,112
  const int grow = b * BROWS + half * 64 + lrow;
  if (grow >= N_NODES) return;
  const unsigned int* hrow = h2u + (size_t)grow * 64 + (ch0 >> 1);
  float o[16];
#pragma unroll
  for (int j = 0; j < 8; ++j) {
    const unsigned int u = hrow[j];
    const float a0 = acc[lrow * 128 + ch0 + 2 * j];
    const float a1 = acc[lrow * 128 + ch0 + 2 * j + 1];
    o[2 * j] = selu1(fmaf(bflo(u), skip[ch0 + 2 * j], a0) + bias[ch0 + 2 * j]);
    o[2 * j + 1] =
        selu1(fmaf(bfhi(u), skip[ch0 + 2 * j + 1], a1) + bias[ch0 + 2 * j + 1]);
  }
#pragma unroll
  for (int q = 0; q < 4; ++q)
    *reinterpret_cast<float4*>(out + (size_t)grow * C + ch0 + 4 * q) =
        make_float4(o[4 * q], o[4 * q + 1], o[4 * q + 2], o[4 * q + 3]);
}

extern "C" void kernel_launch(void* const* d_in, const int* in_sizes, int n_in,
                              void* d_out, int out_size, void* d_ws,
                              size_t ws_size, hipStream_t stream) {
  const float* features = (const float*)d_in[0];  // [n, 256]
  const int* adj_row = (const int*)d_in[1];       // [e]
  const int* adj_col = (const int*)d_in[2];       // [e]
  const float* adj_vals = (const float*)d_in[3];  // [e]
  const float* W = (const float*)d_in[4];         // [256, 128]
  const float* bias = (const float*)d_in[5];      // [128]
  const float* skip = (const float*)d_in[6];      // [128]
  float* out = (float*)d_out;                     // [n, 128]

  char* ws = (char*)d_ws;
  const size_t SZ_H2 = (size_t)N_NODES * C * 2;             // 25.6 MB
  const size_t OFF_RECS = (SZ_H2 + 255) & ~(size_t)255;
  const size_t SZ_RECS = (size_t)NBUCKET * CAP * 8;         // 28.8 MB
  const size_t OFF_GCUR = OFF_RECS + SZ_RECS;
  const size_t SZ_GCUR = (size_t)NBUCKET * 4;               // 3.1 KB
  const size_t OFF_WT = (OFF_GCUR + SZ_GCUR + 255) & ~(size_t)255;
  const size_t NEEDED = OFF_WT + (size_t)D * C * 2;         // ~54.5 MB

  if (ws_size < NEEDED) return;  // round-2 proved ws >= 115 MB

  unsigned short* h2 = (unsigned short*)ws;
  uint2* recs = (uint2*)(ws + OFF_RECS);
  int* gcur = (int*)(ws + OFF_GCUR);
  unsigned short* WT = (unsigned short*)(ws + OFF_WT);

  // 0) WT = bf16(W^T); zero bucket cursors
  prep<<<(D * C) / 256, 256, 0, stream>>>(W, WT);
  hipMemsetAsync(gcur, 0, SZ_GCUR, stream);

  // 1) fused: h2 = bf16(X@W) (MFMA)  ||  bucket partition (block-reserved
  //    contiguous segments -> full-line writes)
  gemm_partition<<<2 * PBLOCKS, 512, 0, stream>>>(
      features, WT, h2, adj_row, adj_col, adj_vals, gcur, recs);

  // 2) per-half-bucket LDS-accumulate gather + skip/bias + SELU
  bucket_gather_selu<<<2 * NBUCKET, 512, 0, stream>>>(
      gcur, recs, (const unsigned int*)h2, skip, bias, out);
}

// Round 11
// 281.975 us; speedup vs baseline: 8.8982x; 8.8982x over previous
//
#include <hip/hip_runtime.h>
#include <math.h>

#define N_NODES 100000
#define D 256
#define C 128
#define N_EDGES 3200000

#define BROWS 128                                // rows per bucket (b = row >> 7)
#define NBUCKET ((N_NODES + BROWS - 1) / BROWS)  // 782
#define CAP 4608                                 // bucket capacity (mean 4096 + 8 sigma)
#define EPB 8192                                 // edges per partition block
#define PBLOCKS ((N_EDGES + EPB - 1) / EPB)      // 391

typedef __attribute__((ext_vector_type(8))) short bf16x8;
typedef __attribute__((ext_vector_type(4))) float f32x4;

// ---------------------------------------------------------------------------
// helpers
// ---------------------------------------------------------------------------
__device__ __forceinline__ unsigned short f2bf(float f) {
  const unsigned int u = __float_as_uint(f);
  return (unsigned short)((u + 0x7fffu + ((u >> 16) & 1u)) >> 16);
}
__device__ __forceinline__ unsigned int pack_bf(float lo, float hi) {
  return (unsigned int)f2bf(lo) | ((unsigned int)f2bf(hi) << 16);
}
__device__ __forceinline__ float bflo(unsigned int u) {
  return __uint_as_float(u << 16);
}
__device__ __forceinline__ float bfhi(unsigned int u) {
  return __uint_as_float(u & 0xffff0000u);
}
__device__ __forceinline__ float selu1(float x) {
  const float scale = 1.0507009873554804934193349852946f;
  const float alpha = 1.6732632423543772848170429916717f;
  return x > 0.f ? scale * x : scale * alpha * (__expf(x) - 1.f);
}
// colval word: col in bits [31:15], bf16(val) sans sign (val>=0) in [14:0]
__device__ __forceinline__ unsigned int pack_rec(int col, float val) {
  return ((unsigned int)col << 15) | ((unsigned int)f2bf(val) & 0x7fffu);
}
__device__ __forceinline__ float rec_val(unsigned int r) {
  return __uint_as_float((r & 0x7fffu) << 16);
}
__device__ __forceinline__ bf16x8 packA_nt(const float* p) {
  const f32x4 a0 = __builtin_nontemporal_load(reinterpret_cast<const f32x4*>(p));
  const f32x4 a1 =
      __builtin_nontemporal_load(reinterpret_cast<const f32x4*>(p) + 1);
  union {
    unsigned int u[4];
    bf16x8 v;
  } af;
  af.u[0] = pack_bf(a0[0], a0[1]);
  af.u[1] = pack_bf(a0[2], a0[3]);
  af.u[2] = pack_bf(a1[0], a1[1]);
  af.u[3] = pack_bf(a1[2], a1[3]);
  return af.v;
}

// ---------------------------------------------------------------------------
// prep: WT[n][k] = bf16(W[k][n])  (64 KB)
// ---------------------------------------------------------------------------
__global__ __launch_bounds__(256) void prep(const float* __restrict__ W,
                                            unsigned short* __restrict__ WT) {
  const int t = blockIdx.x * blockDim.x + threadIdx.x;  // 0..32767
  const int n = t >> 8;
  const int k = t & 255;
  WT[t] = f2bf(W[k * C + n]);
}

// ---------------------------------------------------------------------------
// FUSED gemm + bucket-partition (r10-proven), 512-thr blocks, roles by bid&1.
// ---------------------------------------------------------------------------
__global__ __launch_bounds__(512) void gemm_partition(
    const float* __restrict__ X, const unsigned short* __restrict__ WT,
    unsigned short* __restrict__ h2, const int* __restrict__ row,
    const int* __restrict__ col, const float* __restrict__ vals,
    int* __restrict__ gcur, uint2* __restrict__ recs) {
  __shared__ int hist[NBUCKET];
  __shared__ int run[NBUCKET];
  __shared__ int sbase[NBUCKET];
  const int bid = blockIdx.x;
  const int tid = threadIdx.x;

  if ((bid & 1) == 0) {
    // ---------------- GEMM ----------------
    const int wid = (bid >> 1) * 8 + (tid >> 6);
    const int row0 = wid * 32;
    if (row0 >= N_NODES) return;
    const int lane = tid & 63;
    const int r = lane & 15;   // A row in tile / B col in frag
    const int kg = lane >> 4;  // k-group 0..3

    f32x4 acc[2][8];
#pragma unroll
    for (int g = 0; g < 2; ++g)
#pragma unroll
      for (int f = 0; f < 8; ++f) acc[g][f] = (f32x4){0.f, 0.f, 0.f, 0.f};

    const float* arow0 = X + (size_t)(row0 + r) * D + kg * 8;
    const float* arow1 = arow0 + 16 * D;
    for (int k0 = 0; k0 < D; k0 += 32) {
      const bf16x8 a0 = packA_nt(arow0 + k0);
      const bf16x8 a1 = packA_nt(arow1 + k0);
#pragma unroll
      for (int f = 0; f < 8; ++f) {
        const bf16x8 bf = *reinterpret_cast<const bf16x8*>(
            WT + (size_t)(f * 16 + r) * D + k0 + kg * 8);
        acc[0][f] =
            __builtin_amdgcn_mfma_f32_16x16x32_bf16(a0, bf, acc[0][f], 0, 0, 0);
        acc[1][f] =
            __builtin_amdgcn_mfma_f32_16x16x32_bf16(a1, bf, acc[1][f], 0, 0, 0);
      }
    }
    // C/D layout: col = lane&15, row = (lane>>4)*4 + reg  [m89-verified]
#pragma unroll
    for (int g = 0; g < 2; ++g)
#pragma unroll
      for (int f = 0; f < 8; ++f)
#pragma unroll
        for (int j = 0; j < 4; ++j)
          h2[(size_t)(row0 + g * 16 + kg * 4 + j) * C + f * 16 + r] =
              f2bf(acc[g][f][j]);
  } else {
    // ---------------- PARTITION ----------------
    const int pb = bid >> 1;  // 0..390
    const int e0 = pb * EPB;
    for (int i = tid; i < NBUCKET; i += 512) hist[i] = 0;
    __syncthreads();

    int rstash[16];
#pragma unroll
    for (int k = 0; k < 16; ++k) {
      const int e = e0 + k * 512 + tid;
      int r = -1;
      if (e < N_EDGES) r = __builtin_nontemporal_load(row + e);
      rstash[k] = r;
      if (r >= 0) atomicAdd(&hist[r >> 7], 1);
    }
    __syncthreads();
    for (int b = tid; b < NBUCKET; b += 512) {
      const int h = hist[b];
      sbase[b] = h ? atomicAdd(&gcur[b], h) : 0;
      run[b] = 0;
    }
    __syncthreads();
#pragma unroll
    for (int k = 0; k < 16; ++k) {
      const int r = rstash[k];
      if (r < 0) continue;
      const int e = e0 + k * 512 + tid;
      const int c = __builtin_nontemporal_load(col + e);
      const float v = __builtin_nontemporal_load(vals + e);
      const int b = r >> 7;
      const int pos = sbase[b] + atomicAdd(&run[b], 1);
      if (pos < CAP)
        recs[(size_t)b * CAP + pos] = make_uint2(pack_rec(c, v), r & (BROWS - 1));
    }
  }
}

// ---------------------------------------------------------------------------
// Sort-then-gather + skip/bias + SELU. One WG (512 thr) per bucket (128 rows).
// Phase 1: LDS counting sort of the bucket's records by local row
//          (~9K LDS atomics on 128 counters — NOT per-channel accumulation).
// Phase 2: wave-per-row register gather (r6-proven pattern): records for a
//          row are contiguous in LDS (uniform broadcast reads, conflict-free),
//          4 h2-row gathers in flight, acc in 2 VGPRs/lane, fused epilogue.
// ---------------------------------------------------------------------------
__global__ __launch_bounds__(512) void sort_gather_selu(
    const int* __restrict__ gcur, const uint2* __restrict__ recs,
    const unsigned int* __restrict__ h2u, const float* __restrict__ skip,
    const float* __restrict__ bias, float* __restrict__ out) {
  __shared__ unsigned int sorted[CAP];  // 18.4 KB
  __shared__ int hist[BROWS];
  __shared__ int start[BROWS];  // inclusive scan of hist
  __shared__ int cur[BROWS];
  const int tid = threadIdx.x;
  const int b = blockIdx.x;

  int fill = gcur[b];
  fill = fill < CAP ? fill : CAP;

  if (tid < BROWS) {
    hist[tid] = 0;
    cur[tid] = 0;
  }
  __syncthreads();

  // pass 1: histogram over local rows, stash records in registers
  uint2 stash[9];  // ceil(4608/512)
  int nst = 0;
  for (int i = tid; i < fill; i += 512) {
    const uint2 rc = recs[(size_t)b * CAP + i];
    stash[nst++] = rc;
    atomicAdd(&hist[rc.y], 1);
  }
  __syncthreads();

  // inclusive Hillis-Steele scan of hist -> start (128 elements, 7 steps)
  if (tid < BROWS) start[tid] = hist[tid];
  __syncthreads();
  for (int off = 1; off < BROWS; off <<= 1) {
    int t = 0;
    if (tid < BROWS && tid >= off) t = start[tid - off];
    __syncthreads();
    if (tid < BROWS) start[tid] += t;
    __syncthreads();
  }

  // pass 2: scatter colvals into row-contiguous order
  for (int k = 0; k < nst; ++k) {
    const uint2 rc = stash[k];
    const int lr = (int)rc.y;
    const int pos = start[lr] - hist[lr] + atomicAdd(&cur[lr], 1);
    sorted[pos] = rc.x;
  }
  __syncthreads();

  // phase 2: wave wv handles local rows wv, wv+8, ... (16 rows each)
  const int lane = tid & 63;
  const int wv = tid >> 6;
  for (int lr = wv; lr < BROWS; lr += 8) {
    const int grow = b * BROWS + lr;
    if (grow >= N_NODES) break;  // only trims tail of last bucket
    const int je = start[lr];
    int j = je - hist[lr];
    float ax = 0.f, ay = 0.f;
    for (; j + 3 < je; j += 4) {
      const unsigned int c0 = sorted[j];
      const unsigned int c1 = sorted[j + 1];
      const unsigned int c2 = sorted[j + 2];
      const unsigned int c3 = sorted[j + 3];
      const unsigned int u0 = h2u[(size_t)(c0 >> 15) * 64 + lane];
      const unsigned int u1 = h2u[(size_t)(c1 >> 15) * 64 + lane];
      const unsigned int u2 = h2u[(size_t)(c2 >> 15) * 64 + lane];
      const unsigned int u3 = h2u[(size_t)(c3 >> 15) * 64 + lane];
      ax = fmaf(rec_val(c0), bflo(u0), ax);
      ay = fmaf(rec_val(c0), bfhi(u0), ay);
      ax = fmaf(rec_val(c1), bflo(u1), ax);
      ay = fmaf(rec_val(c1), bfhi(u1), ay);
      ax = fmaf(rec_val(c2), bflo(u2), ax);
      ay = fmaf(rec_val(c2), bfhi(u2), ay);
      ax = fmaf(rec_val(c3), bflo(u3), ax);
      ay = fmaf(rec_val(c3), bfhi(u3), ay);
    }
    for (; j < je; ++j) {
      const unsigned int cc = sorted[j];
      const unsigned int u = h2u[(size_t)(cc >> 15) * 64 + lane];
      ax = fmaf(rec_val(cc), bflo(u), ax);
      ay = fmaf(rec_val(cc), bfhi(u), ay);
    }
    // epilogue: out = selu(h*skip + agg + bias)
    const unsigned int hr = h2u[(size_t)grow * 64 + lane];
    const float2 sk = *reinterpret_cast<const float2*>(skip + lane * 2);
    const float2 bi = *reinterpret_cast<const float2*>(bias + lane * 2);
    const float ox = selu1(fmaf(bflo(hr), sk.x, ax) + bi.x);
    const float oy = selu1(fmaf(bfhi(hr), sk.y, ay) + bi.y);
    *reinterpret_cast<float2*>(out + (size_t)grow * C + lane * 2) =
        make_float2(ox, oy);
  }
}

extern "C" void kernel_launch(void* const* d_in, const int* in_sizes, int n_in,
                              void* d_out, int out_size, void* d_ws,
                              size_t ws_size, hipStream_t stream) {
  const float* features = (const float*)d_in[0];  // [n, 256]
  const int* adj_row = (const int*)d_in[1];       // [e]
  const int* adj_col = (const int*)d_in[2];       // [e]
  const float* adj_vals = (const float*)d_in[3];  // [e]
  const float* W = (const float*)d_in[4];         // [256, 128]
  const float* bias = (const float*)d_in[5];      // [128]
  const float* skip = (const float*)d_in[6];      // [128]
  float* out = (float*)d_out;                     // [n, 128]

  char* ws = (char*)d_ws;
  const size_t SZ_H2 = (size_t)N_NODES * C * 2;      // 25.6 MB
  const size_t OFF_RECS = (SZ_H2 + 255) & ~(size_t)255;
  const size_t SZ_RECS = (size_t)NBUCKET * CAP * 8;  // 28.8 MB
  const size_t OFF_GCUR = OFF_RECS + SZ_RECS;
  const size_t SZ_GCUR = (size_t)NBUCKET * 4;        // 3.1 KB
  const size_t OFF_WT = (OFF_GCUR + SZ_GCUR + 255) & ~(size_t)255;
  const size_t NEEDED = OFF_WT + (size_t)D * C * 2;  // ~54.5 MB

  if (ws_size < NEEDED) return;  // round-2 proved ws >= 115 MB

  unsigned short* h2 = (unsigned short*)ws;
  uint2* recs = (uint2*)(ws + OFF_RECS);
  int* gcur = (int*)(ws + OFF_GCUR);
  unsigned short* WT = (unsigned short*)(ws + OFF_WT);

  // 0) WT = bf16(W^T); zero bucket cursors
  prep<<<(D * C) / 256, 256, 0, stream>>>(W, WT);
  hipMemsetAsync(gcur, 0, SZ_GCUR, stream);

  // 1) fused: h2 = bf16(X@W) (MFMA)  ||  bucket partition
  gemm_partition<<<2 * PBLOCKS, 512, 0, stream>>>(
      features, WT, h2, adj_row, adj_col, adj_vals, gcur, recs);

  // 2) per-bucket counting-sort + wave-per-row gather + skip/bias + SELU
  sort_gather_selu<<<NBUCKET, 512, 0, stream>>>(
      gcur, recs, (const unsigned int*)h2, skip, bias, out);
}